// Round 3
// baseline (211.923 us; speedup 1.0000x reference)
//
#include <hip/hip_runtime.h>
#include <math.h>

// Problem constants (fixed by the reference)
namespace {
constexpr int IN_DIMc = 159;   // L1*(DIM+1)+L2
constexpr int MDIMc   = 93;    // L2*DIM
constexpr int MATELc  = 2976;  // banded tril nnz
constexpr int ROWS    = MDIMc + MATELc;  // 3069
constexpr int LPATHc  = 63;
constexpr int SIGDIMc = 340;   // 4+16+64+256
constexpr int NCLSc   = 10;
}

// Device-global scratch for the [B, 3069] mean|cov intermediate.
// Static __device__ storage avoids any assumption about ws_size (an OOB
// write into an undersized d_ws would fault the GPU). Fully rewritten on
// every launch; rows 3069..3071 are never read.
__device__ float g_mc[256 * 3072];

// --------------------------------------------------------------------------
// Kernel 1: g_mc[b][r] = dot(x[b,:159], Wcat[r,:159]) + bcat[r]
// Wcat = [W_mean ; W_cov] (3069 rows). Tile: 64 rows x 32 batches per block.
// --------------------------------------------------------------------------
__global__ __launch_bounds__(256) void gemm_mc(
    const float* __restrict__ x, const float* __restrict__ Wm,
    const float* __restrict__ bm, const float* __restrict__ Wc,
    const float* __restrict__ bc)
{
  __shared__ float xls[32 * 160];   // [batch][159] (stride 160)
  __shared__ float wls[64 * 161];   // [row][159] (stride 161, bank-spread)
  const int t  = threadIdx.x;
  const int r0 = blockIdx.x * 64;
  const int b0 = blockIdx.y * 32;

  for (int idx = t; idx < 32 * IN_DIMc; idx += 256) {
    int bb = idx / IN_DIMc, ii = idx - bb * IN_DIMc;
    xls[bb * 160 + ii] = x[(b0 + bb) * IN_DIMc + ii];
  }
  for (int idx = t; idx < 64 * IN_DIMc; idx += 256) {
    int rr = idx / IN_DIMc, ii = idx - rr * IN_DIMc;
    int r = r0 + rr;
    float v = 0.0f;
    if (r < MDIMc)      v = Wm[r * IN_DIMc + ii];
    else if (r < ROWS)  v = Wc[(r - MDIMc) * IN_DIMc + ii];
    wls[rr * 161 + ii] = v;
  }
  __syncthreads();

  const int rl = t & 63;    // row within tile (lane -> coalesced stores)
  const int bg = t >> 6;    // batch group 0..3, 8 batches each
  float acc[8] = {0, 0, 0, 0, 0, 0, 0, 0};
  for (int i = 0; i < IN_DIMc; ++i) {
    float wv = wls[rl * 161 + i];
#pragma unroll
    for (int j = 0; j < 8; ++j)
      acc[j] = fmaf(wv, xls[(bg * 8 + j) * 160 + i], acc[j]);
  }
  const int r = r0 + rl;
  if (r < ROWS) {
    float bias = (r < MDIMc) ? bm[r] : bc[r - MDIMc];
#pragma unroll
    for (int j = 0; j < 8; ++j)
      g_mc[(size_t)(b0 + bg * 8 + j) * ROWS + r] = acc[j] + bias;
  }
}

// --------------------------------------------------------------------------
// Kernel 2: one block (512 threads = 8 waves) per batch.
//  P0: stage x, mean, cov, eps in LDS
//  P1: newV[93][64] = banded-tril(cov) @ eps + mean
//  P2: each wave handles 8 of the K=64 paths; per path: build 63x4 point
//      buffer, 62 Chen steps (shuffle-free lane layout), norm reduction,
//      40-iter bisection for lambda, scale + accumulate.
//  P3: cross-wave reduce -> sig[340]; fused 340x10 linear + log_softmax.
// Lane layout: l = a*16+b*4+c. Lane holds S4[4l..4l+3], S3[l],
// S2[l>>2] (x4 replicated), S1[l>>4] (x16 replicated).
// --------------------------------------------------------------------------
__global__ __launch_bounds__(512) void path_sig(
    const float* __restrict__ x,
    const float* __restrict__ eps, const float* __restrict__ Wf,
    const float* __restrict__ bf, float* __restrict__ out)
{
  // LDS packing (floats). eps region (2976..8928) is dead after P1 and is
  // reused for pbuf/part/sig/logits. Total 15232 floats = 60928 B < 64 KB.
  constexpr int OFF_COV  = 0;      // 2976
  constexpr int OFF_EPS  = 2976;   // 5952  [93][64]
  constexpr int OFF_PBUF = 2976;   // alias: 8 waves * 63 pts * 4 ch = 2016
  constexpr int OFF_PART = 4992;   // alias: 8 * 340 = 2720
  constexpr int OFF_SIG  = 7712;   // alias: 340
  constexpr int OFF_LOG  = 8052;   // alias: 16
  constexpr int OFF_MEAN = 8928;   // 96
  constexpr int OFF_XS   = 9024;   // 160
  constexpr int OFF_NEWV = 9184;   // 93*65 = 6045 (stride 65: bank spread)
  __shared__ __align__(16) float smem[15232];
  float* covL  = smem + OFF_COV;
  float* epsL  = smem + OFF_EPS;
  float* meanL = smem + OFF_MEAN;
  float* xsm   = smem + OFF_XS;
  float* newVL = smem + OFF_NEWV;

  const int t = threadIdx.x;
  const int b = blockIdx.x;

  // ---- P0: stage inputs ----
  for (int i = t; i < IN_DIMc; i += 512) xsm[i] = x[b * IN_DIMc + i];
  for (int i = t; i < MDIMc; i += 512) meanL[i] = g_mc[(size_t)b * ROWS + i];
  for (int i = t; i < MATELc; i += 512)
    covL[i] = g_mc[(size_t)b * ROWS + MDIMc + i];
  {
    const float4* ep4 = (const float4*)(eps + (size_t)b * MDIMc * 64);
    float4* el4 = (float4*)epsL;
    for (int i = t; i < MDIMc * 16; i += 512) el4[i] = ep4[i];
  }
  __syncthreads();

  // ---- P1: newV = M @ eps + mean (M = banded block-tril, hard-coded) ----
  const int k  = t & 63;
  const int rg = t >> 6;
  for (int r = rg; r < MDIMc; r += 8) {
    const int X  = r / 3;
    const int tr = r - X * 3;
    float acc = meanL[r];
    const int tb = (tr * (tr + 1)) >> 1;
    for (int y = 0; y <= X; ++y) {
      const int i = X - y;                              // diagonal offset
      const int base = 6 * (31 * i - ((i * (i - 1)) >> 1)) + y * 6 + tb;
      for (int tc = 0; tc <= tr; ++tc)
        acc = fmaf(covL[base + tc], epsL[(y * 3 + tc) * 64 + k], acc);
    }
    newVL[r * 65 + k] = acc;
  }
  __syncthreads();

  // ---- P2: signatures ----
  const int w = rg;          // wave 0..7
  const int l = k;           // lane 0..63
  const int la = l >> 4, lb = (l >> 2) & 3, lc = l & 3;
  float* pb = smem + OFF_PBUF + w * (LPATHc * 4);
  float acc1 = 0.f, acc2 = 0.f, acc3 = 0.f;
  float4 acc4 = make_float4(0.f, 0.f, 0.f, 0.f);
  const float inv6 = 1.0f / 6.0f, inv24 = 1.0f / 24.0f;

#pragma unroll 1
  for (int j = 0; j < 8; ++j) {
    const int kk = w * 8 + j;
    // build path point buffer [63][4]: even pos = old pt, odd pos = newV pt
    if (l < LPATHc) {
      const int m = l >> 1;
      float4 pt;
      if ((l & 1) == 0) {
        pt.x = xsm[3 * m]; pt.y = xsm[3 * m + 1]; pt.z = xsm[3 * m + 2];
        pt.w = xsm[96 + m];
      } else {
        pt.x = newVL[(3 * m) * 65 + kk];
        pt.y = newVL[(3 * m + 1) * 65 + kk];
        pt.z = newVL[(3 * m + 2) * 65 + kk];
        pt.w = xsm[128 + m];
      }
      *(float4*)(pb + l * 4) = pt;
    }
    __syncthreads();   // uniform across all 8 waves (loop count uniform)

    float s1a = 0.f, s2o = 0.f, s3 = 0.f;
    float4 s4 = make_float4(0.f, 0.f, 0.f, 0.f);
    float4 po = *(const float4*)pb;
    float pao = pb[la], pbo = pb[lb], pco = pb[lc];
#pragma unroll 2
    for (int i = 1; i < LPATHc; ++i) {
      float4 pn = *(const float4*)(pb + i * 4);
      float pan = pb[i * 4 + la], pbn = pb[i * 4 + lb], pcn = pb[i * 4 + lc];
      float dxa = pan - pao, dxb = pbn - pbo, dxc = pcn - pco;
      float d0 = pn.x - po.x, d1 = pn.y - po.y, d2 = pn.z - po.z, d3 = pn.w - po.w;
      float bcv = dxb * dxc;
      // T4[abcd] = S4 + dxd*(dxa*bc/24 + S1[a]*bc/6 + S2[ab]*dxc/2 + S3[abc])
      float coef = fmaf(fmaf(s1a, inv6, dxa * inv24), bcv,
                        fmaf(s2o, dxc * 0.5f, s3));
      s4.x = fmaf(coef, d0, s4.x);
      s4.y = fmaf(coef, d1, s4.y);
      s4.z = fmaf(coef, d2, s4.z);
      s4.w = fmaf(coef, d3, s4.w);
      // T3[abc] = S3 + dxa*bc/6 + S1[a]*bc/2 + S2[ab]*dxc
      s3 = fmaf(fmaf(s1a, 0.5f, dxa * inv6), bcv, fmaf(s2o, dxc, s3));
      // T2[ab] = S2 + dxb*(dxa/2 + S1[a])
      s2o = fmaf(dxb, fmaf(dxa, 0.5f, s1a), s2o);
      // T1[a] = S1 + dxa
      s1a += dxa;
      po = pn; pao = pan; pbo = pbn; pco = pcn;
    }

    // ---- tensor normalization (Chevyrev-Oberhauser) ----
    float c4 = s4.x * s4.x + s4.y * s4.y + s4.z * s4.z + s4.w * s4.w;
    float c3v = s3 * s3;
    float c2v = (lc == 0) ? s2o * s2o : 0.f;          // count each S2 once
    float c1v = ((l & 15) == 0) ? s1a * s1a : 0.f;    // count each S1 once
#pragma unroll
    for (int off = 1; off < 64; off <<= 1) {
      c1v += __shfl_xor(c1v, off);
      c2v += __shfl_xor(c2v, off);
      c3v += __shfl_xor(c3v, off);
      c4  += __shfl_xor(c4, off);
    }
    float norm2 = 1.f + c1v + c2v + c3v + c4;
    // phi with C=4, A=1: x<=4 ? x : 8 - 16/x
    float psi = (norm2 <= 4.f) ? norm2 : (8.f - 16.f / norm2);
    float lo = 0.f, hi = 1.f;
#pragma unroll 1
    for (int it = 0; it < 40; ++it) {
      float mid = 0.5f * (lo + hi);
      float m2 = mid * mid;
      float val = fmaf(m2, fmaf(m2, fmaf(m2, fmaf(m2, c4, c3v), c2v), c1v), 1.f);
      bool pos = val > psi;
      hi = pos ? mid : hi;
      lo = pos ? lo : mid;
    }
    float lam = 0.5f * (lo + hi);
    float lam2 = lam * lam;
    float lam3 = lam2 * lam, lam4 = lam2 * lam2;
    acc1 = fmaf(s1a, lam, acc1);
    acc2 = fmaf(s2o, lam2, acc2);
    acc3 = fmaf(s3, lam3, acc3);
    acc4.x = fmaf(s4.x, lam4, acc4.x);
    acc4.y = fmaf(s4.y, lam4, acc4.y);
    acc4.z = fmaf(s4.z, lam4, acc4.z);
    acc4.w = fmaf(s4.w, lam4, acc4.w);
  }

  // ---- P3: reduce over waves, final linear + log_softmax ----
  {
    float* part = smem + OFF_PART + w * SIGDIMc;
    if ((l & 15) == 0) part[l >> 4] = acc1;        // S1[0..3]
    if (lc == 0)       part[4 + (l >> 2)] = acc2;  // S2[0..15]
    part[20 + l] = acc3;                           // S3[0..63]
    *(float4*)(part + 84 + 4 * l) = acc4;          // S4[0..255]
  }
  __syncthreads();

  float* sig = smem + OFF_SIG;
  for (int jj = t; jj < SIGDIMc; jj += 512) {
    float s = 0.f;
#pragma unroll
    for (int ww = 0; ww < 8; ++ww) s += smem[OFF_PART + ww * SIGDIMc + jj];
    sig[jj] = s * (1.0f / 64.0f);                  // mean over K
  }
  __syncthreads();

  float* logits = smem + OFF_LOG;
  for (int c = w; c < NCLSc; c += 8) {
    float s = 0.f;
    for (int jj = l; jj < SIGDIMc; jj += 64)
      s = fmaf(sig[jj], Wf[c * SIGDIMc + jj], s);
#pragma unroll
    for (int off = 1; off < 64; off <<= 1) s += __shfl_xor(s, off);
    if (l == 0) logits[c] = s + bf[c];
  }
  __syncthreads();
  if (t < NCLSc) {
    float mx = logits[0];
#pragma unroll
    for (int i2 = 1; i2 < NCLSc; ++i2) mx = fmaxf(mx, logits[i2]);
    float se = 0.f;
#pragma unroll
    for (int i2 = 0; i2 < NCLSc; ++i2) se += expf(logits[i2] - mx);
    out[b * NCLSc + t] = logits[t] - mx - logf(se);
  }
}

extern "C" void kernel_launch(void* const* d_in, const int* in_sizes, int n_in,
                              void* d_out, int out_size, void* d_ws, size_t ws_size,
                              hipStream_t stream) {
  (void)in_sizes; (void)n_in; (void)out_size; (void)d_ws; (void)ws_size;
  const float* x   = (const float*)d_in[0];
  const float* Wm  = (const float*)d_in[1];
  const float* bm  = (const float*)d_in[2];
  const float* Wc  = (const float*)d_in[3];
  const float* bcv = (const float*)d_in[4];
  const float* Wf  = (const float*)d_in[5];
  const float* bf  = (const float*)d_in[6];
  const float* eps = (const float*)d_in[7];
  // d_in[8]/d_in[9] (x_idx/y_idx) are compile-time deterministic; hard-coded.
  float* out = (float*)d_out;

  gemm_mc<<<dim3(48, 8), 256, 0, stream>>>(x, Wm, bm, Wc, bcv);
  path_sig<<<dim3(256), 512, 0, stream>>>(x, eps, Wf, bf, out);
}